// Round 2
// baseline (65.105 us; speedup 1.0000x reference)
//
#include <hip/hip_runtime.h>

// LensCrackFault: out = clip(where(bresenham_mask, 0.05, x), 0, 1)
// x: float32 [32, 3, 512, 512]; endpoints: int32 [32, 6, 4] = (y0,x0,y1,x1)
//
// Gotcha replicated from the JAX reference: inactive scan steps emit (-1,-1),
// and .at[].set(mode='drop') WRAPS negative indices before the drop check, so
// every line with nsteps < 511 also paints pixel (511, 511) of its image.

#define BB 32
#define CH 3
#define HH 512
#define WW 512
#define NLINES 6
#define CRACK_VAL 0.05f

// Kernel 1: out = clip(x, 0, 1), vectorized float4, grid-stride.
__global__ void lens_clip_copy(const float4* __restrict__ in,
                               float4* __restrict__ out, int n4) {
    int stride = gridDim.x * blockDim.x;
    for (int i = blockIdx.x * blockDim.x + threadIdx.x; i < n4; i += stride) {
        float4 v = in[i];
        v.x = fminf(fmaxf(v.x, 0.0f), 1.0f);
        v.y = fminf(fmaxf(v.y, 0.0f), 1.0f);
        v.z = fminf(fmaxf(v.z, 0.0f), 1.0f);
        v.w = fminf(fmaxf(v.w, 0.0f), 1.0f);
        out[i] = v;
    }
}

// Kernel 2: one thread per (line, channel). Replays the reference's exact
// Bresenham recurrence (emit BEFORE step; both-axis conditional step;
// nsteps = max(dx,dy), emitting nsteps+1 pixels) and writes 0.05 directly.
// Plus the negative-index-wrap pixel at (511,511) when nsteps < 511.
__global__ void lens_draw_lines(const int* __restrict__ ep,
                                float* __restrict__ out) {
    int tid = blockIdx.x * blockDim.x + threadIdx.x;
    if (tid >= BB * NLINES * CH) return;
    int line = tid / CH;
    int c = tid - line * CH;
    int b = line / NLINES;

    const int* e = ep + line * 4;
    int y0 = e[0], x0 = e[1], y1 = e[2], x1 = e[3];

    int dx = abs(x1 - x0);
    int dy = abs(y1 - y0);
    int sx = (x0 < x1) ? 1 : -1;
    int sy = (y0 < y1) ? 1 : -1;
    int nsteps = max(dx, dy);
    int err = dx - dy;
    int cx = x0, cy = y0;

    float* base = out + ((size_t)b * CH + c) * (size_t)(HH * WW);
    for (int t = 0; t <= nsteps; ++t) {
        base[cy * WW + cx] = CRACK_VAL;
        int e2 = 2 * err;
        if (e2 > -dy) { err -= dy; cx += sx; }
        if (e2 <  dx) { err += dx; cy += sy; }
    }

    // Reference's scan runs T=512 steps; steps t in (nsteps, 512) emit
    // (-1,-1), which JAX wraps to (511,511) before the 'drop' check.
    if (nsteps < HH - 1) {
        base[(HH - 1) * WW + (WW - 1)] = CRACK_VAL;
    }
}

extern "C" void kernel_launch(void* const* d_in, const int* in_sizes, int n_in,
                              void* d_out, int out_size, void* d_ws, size_t ws_size,
                              hipStream_t stream) {
    const float* x = (const float*)d_in[0];
    const int* endpoints = (const int*)d_in[1];
    float* out = (float*)d_out;

    int n = in_sizes[0];          // 32*3*512*512 = 25165824
    int n4 = n / 4;               // 6291456 float4s

    // Memory-bound copy: cap grid at 2048 blocks, grid-stride.
    int blocks = 2048;
    lens_clip_copy<<<blocks, 256, 0, stream>>>(
        (const float4*)x, (float4*)out, n4);

    // 32*6*3 = 576 threads; 9 blocks of 64.
    int nthreads = BB * NLINES * CH;
    lens_draw_lines<<<(nthreads + 63) / 64, 64, 0, stream>>>(endpoints, out);
}

// Round 3
// 39.410 us; speedup vs baseline: 1.6520x; 1.6520x over previous
//
#include <hip/hip_runtime.h>

// LensCrackFault: out = clip(where(bresenham_mask, 0.05, x), 0, 1)
// x: float32 [32, 3, 512, 512]; endpoints: int32 [32, 6, 4] = (y0,x0,y1,x1)
//
// Reference gotchas replicated:
//  - inactive scan steps emit (-1,-1); JAX .at[].set(mode='drop') wraps
//    negatives first, so any line with nsteps < 511 also paints (511,511).
//  - emit-before-step Bresenham, nsteps = max(dx,dy), nsteps+1 pixels.
//
// Closed form of the reference's dual-condition Bresenham (verified vs the
// recurrence): for dx>=dy the major axis advances every step and
//   y_t = y0 + sy * max(0, ceil((2*t*dy - dx) / (2*dx)))
// (symmetric for dy>dx). This makes every pixel independently computable,
// so the rasterizer is one thread per (line, t) instead of a 512-long
// serial dependence chain.

#define BB 32
#define CH 3
#define HH 512
#define WW 512
#define NLINES 6
#define CRACK_VAL 0.05f
#define UNROLL 4
#define COPY_BLOCKS 3072
#define COPY_TPB 256

// Kernel 1: out = clip(x, 0, 1); 4 independent float4 loads in flight.
__global__ void lens_clip_copy(const float4* __restrict__ in,
                               float4* __restrict__ out, int n4) {
    int tid = blockIdx.x * blockDim.x + threadIdx.x;
    int nth = gridDim.x * blockDim.x;
    int chunk = UNROLL * nth;
    int nfull = n4 / chunk;
    int i = tid;
    for (int c = 0; c < nfull; ++c) {
        float4 v[UNROLL];
#pragma unroll
        for (int u = 0; u < UNROLL; ++u) v[u] = in[i + u * nth];
#pragma unroll
        for (int u = 0; u < UNROLL; ++u) {
            float4 w = v[u];
            w.x = fminf(fmaxf(w.x, 0.0f), 1.0f);
            w.y = fminf(fmaxf(w.y, 0.0f), 1.0f);
            w.z = fminf(fmaxf(w.z, 0.0f), 1.0f);
            w.w = fminf(fmaxf(w.w, 0.0f), 1.0f);
            out[i + u * nth] = w;
        }
        i += chunk;
    }
    // tail (not taken for the bench shape, kept for generality)
    for (int j = nfull * chunk + tid; j < n4; j += nth) {
        float4 w = in[j];
        w.x = fminf(fmaxf(w.x, 0.0f), 1.0f);
        w.y = fminf(fmaxf(w.y, 0.0f), 1.0f);
        w.z = fminf(fmaxf(w.z, 0.0f), 1.0f);
        w.w = fminf(fmaxf(w.w, 0.0f), 1.0f);
        out[j] = w;
    }
}

// Kernel 2: one thread per (line, t), t in [0,512). Closed-form Bresenham
// position; writes 0.05 to all 3 channels. t == nsteps+1 (when it exists,
// i.e. nsteps < 511) handles the negative-index-wrap pixel (511,511).
__global__ void lens_draw_lines(const int* __restrict__ ep,
                                float* __restrict__ out) {
    int tid = blockIdx.x * blockDim.x + threadIdx.x;
    int line = tid >> 9;          // / 512
    int t = tid & 511;
    if (line >= BB * NLINES) return;

    const int* e = ep + line * 4;
    int y0 = e[0], x0 = e[1], y1 = e[2], x1 = e[3];

    int dx = abs(x1 - x0);
    int dy = abs(y1 - y0);
    int sx = (x0 < x1) ? 1 : -1;
    int sy = (y0 < y1) ? 1 : -1;
    int nsteps = max(dx, dy);

    int cy, cx;
    if (t == 0) {
        cy = y0; cx = x0;
    } else if (t <= nsteps) {
        if (dx >= dy) {            // dx >= 1 here since t >= 1
            int num = 2 * t * dy - dx;
            int S = (num <= 0) ? 0 : (num + 2 * dx - 1) / (2 * dx);
            cx = x0 + sx * t;
            cy = y0 + sy * S;
        } else {                   // dy > dx => dy >= 1
            int num = 2 * t * dx - dy;
            int S = (num <= 0) ? 0 : (num + 2 * dy - 1) / (2 * dy);
            cy = y0 + sy * t;
            cx = x0 + sx * S;
        }
    } else if (t == nsteps + 1) {
        // reference scan's first inactive step: (-1,-1) wraps to (511,511)
        cy = HH - 1; cx = WW - 1;
    } else {
        return;
    }

    int b = line / NLINES;
    size_t off = (size_t)b * CH * HH * WW + (size_t)cy * WW + cx;
    out[off] = CRACK_VAL;
    out[off + (size_t)HH * WW] = CRACK_VAL;
    out[off + (size_t)2 * HH * WW] = CRACK_VAL;
}

extern "C" void kernel_launch(void* const* d_in, const int* in_sizes, int n_in,
                              void* d_out, int out_size, void* d_ws, size_t ws_size,
                              hipStream_t stream) {
    const float* x = (const float*)d_in[0];
    const int* endpoints = (const int*)d_in[1];
    float* out = (float*)d_out;

    int n = in_sizes[0];          // 32*3*512*512 = 25165824
    int n4 = n / 4;               // 6291456 float4s

    lens_clip_copy<<<COPY_BLOCKS, COPY_TPB, 0, stream>>>(
        (const float4*)x, (float4*)out, n4);

    // 192 lines * 512 steps = 98304 threads
    int nthreads = BB * NLINES * 512;
    lens_draw_lines<<<nthreads / 256, 256, 0, stream>>>(endpoints, out);
}